// Round 1
// baseline (733.887 us; speedup 1.0000x reference)
//
#include <hip/hip_runtime.h>
#include <math.h>

// GAT predictor: B=64, N=512, ATOM=34, GAT=128, HID=256, 3 layers + out layer.
// fp32 baseline. ws layout (floats):
//   Wh    [64*512*128]           off 0
//   src   [64*512]               off 4194304
//   dst   [64*512]               off 4227072
//   multi [64*512*384]           off 4259840   (x aliases multi once multi is dead)
// total ~64.3 MB.

#define ALPHA 0.2f
#define NEG_INF -9e15f

// C[row, g0+c] = act( sum_k A[row,k]*W[k, g0+c] (+bias) )
// A: [R,K] contiguous. Tile 32 rows x 128 cols, K-chunk 32.
__global__ __launch_bounds__(256) void gemm_kernel(
    const float* __restrict__ A, const float* __restrict__ W,
    const float* __restrict__ bias, float* __restrict__ C,
    const int K, const int G, const int c_rstride, const int c_coff, const int mode)
{
  __shared__ float AsT[32][36];   // [kk][row], padded: 2-way max write conflict, 16B-aligned rows
  __shared__ float Ws[32][128];   // [kk][g]
  const int t = threadIdx.x;
  const long row0 = (long)blockIdx.z * 512 + blockIdx.x * 32;
  const int g0 = blockIdx.y * 128;
  const int c = t & 127, rg = t >> 7;
  float acc[16];
#pragma unroll
  for (int i = 0; i < 16; i++) acc[i] = 0.f;

  for (int k0 = 0; k0 < K; k0 += 32) {
    {
      int idx = t;
#pragma unroll
      for (int i = 0; i < 4; i++, idx += 256) {
        int r = idx >> 5, kk = idx & 31;
        float v = 0.f;
        if (k0 + kk < K) v = A[(row0 + r) * K + k0 + kk];
        AsT[kk][r] = v;
      }
    }
    {
      int idx = t;
#pragma unroll
      for (int i = 0; i < 16; i++, idx += 256) {
        int kk = idx >> 7, g = idx & 127;
        float v = 0.f;
        if (k0 + kk < K) v = W[(long)(k0 + kk) * G + g0 + g];
        Ws[kk][g] = v;
      }
    }
    __syncthreads();
#pragma unroll 4
    for (int kk = 0; kk < 32; kk++) {
      float wv = Ws[kk][c];
      const float4* ap = (const float4*)&AsT[kk][rg * 16];
      float4 a0 = ap[0], a1 = ap[1], a2 = ap[2], a3 = ap[3];
      acc[0]  += a0.x * wv; acc[1]  += a0.y * wv; acc[2]  += a0.z * wv; acc[3]  += a0.w * wv;
      acc[4]  += a1.x * wv; acc[5]  += a1.y * wv; acc[6]  += a1.z * wv; acc[7]  += a1.w * wv;
      acc[8]  += a2.x * wv; acc[9]  += a2.y * wv; acc[10] += a2.z * wv; acc[11] += a2.w * wv;
      acc[12] += a3.x * wv; acc[13] += a3.y * wv; acc[14] += a3.z * wv; acc[15] += a3.w * wv;
    }
    __syncthreads();
  }
#pragma unroll
  for (int r = 0; r < 16; r++) {
    float v = acc[r];
    if (mode == 1) {
      v += bias[g0 + c];
      v = v > 0.f ? v : ALPHA * v;
    }
    C[(row0 + rg * 16 + r) * c_rstride + c_coff + g0 + c] = v;
  }
}

// src[row] = Wh[row,:].a[0:128], dst[row] = Wh[row,:].a[128:256]. One wave per row.
__global__ __launch_bounds__(256) void srcdst_kernel(
    const float* __restrict__ Wh, const float* __restrict__ a,
    float* __restrict__ src, float* __restrict__ dst)
{
  const int row = blockIdx.x * 4 + (threadIdx.x >> 6);
  const int lane = threadIdx.x & 63;
  const float* w = Wh + (long)row * 128;
  float w0 = w[lane], w1 = w[lane + 64];
  float s = w0 * a[lane] + w1 * a[lane + 64];
  float d = w0 * a[128 + lane] + w1 * a[192 + lane];
#pragma unroll
  for (int m = 1; m < 64; m <<= 1) {
    s += __shfl_xor(s, m, 64);
    d += __shfl_xor(d, m, 64);
  }
  if (lane == 0) { src[row] = s; dst[row] = d; }
}

// Fused attention row-block: 16 i-rows x all 512 j. softmax(mask(leaky(src_i+dst_j))) @ Wh, elu.
__global__ __launch_bounds__(256) void attn_kernel(
    const float* __restrict__ Wh,   // [B*512,128] (this layer)
    const int*   __restrict__ adj,  // [B,512,512]
    const float* __restrict__ src, const float* __restrict__ dst,  // [B*512]
    float* __restrict__ out, const int ostride, const int ocoff)
{
  __shared__ float pT[512][20];    // [j][row], 40KB; rows 16B-aligned (80B)
  __shared__ float sinv[16];
  const int t = threadIdx.x;
  const long base = (long)blockIdx.y * 512;
  const int i0 = blockIdx.x * 16;

  // phase 1: scores, row-max, exp, row-sum (16 threads per row, 32 j's each, regs only)
  {
    const int r = t >> 4, l16 = t & 15;
    const long i = base + i0 + r;
    const float si = src[i];
    const int* __restrict__ arow = adj + i * 512;
    const float* __restrict__ drow = dst + base;
    float sv[32];
    float m = -INFINITY;
#pragma unroll
    for (int jj = 0; jj < 32; jj++) {
      int j = l16 + (jj << 4);
      float e = si + drow[j];
      e = e > 0.f ? e : ALPHA * e;
      float s = (arow[j] > 0) ? e : NEG_INF;
      sv[jj] = s;
      m = fmaxf(m, s);
    }
#pragma unroll
    for (int w = 1; w < 16; w <<= 1) m = fmaxf(m, __shfl_xor(m, w, 16));
    float sum = 0.f;
#pragma unroll
    for (int jj = 0; jj < 32; jj++) {
      int j = l16 + (jj << 4);
      float p = __expf(sv[jj] - m);
      pT[j][r] = p;
      sum += p;
    }
#pragma unroll
    for (int w = 1; w < 16; w <<= 1) sum += __shfl_xor(sum, w, 16);
    if (l16 == 0) sinv[r] = 1.f / sum;
  }
  __syncthreads();

  // phase 3: out[r, c] = sum_j p[r][j] * Wh[j, c]. thread = (c in [0,128), jh half of j).
  const int c = t & 127, jh = t >> 7;
  float acc[16];
#pragma unroll
  for (int r = 0; r < 16; r++) acc[r] = 0.f;
  const float* __restrict__ whp = Wh + (base + jh * 256) * 128 + c;
  const float (* __restrict__ pTh)[20] = (const float (*)[20])&pT[jh * 256];
#pragma unroll 4
  for (int j = 0; j < 256; j++) {
    float w = whp[j * 128];
    const float4* pv = (const float4*)&pTh[j][0];
    float4 p0 = pv[0], p1 = pv[1], p2 = pv[2], p3 = pv[3];
    acc[0]  += p0.x * w; acc[1]  += p0.y * w; acc[2]  += p0.z * w; acc[3]  += p0.w * w;
    acc[4]  += p1.x * w; acc[5]  += p1.y * w; acc[6]  += p1.z * w; acc[7]  += p1.w * w;
    acc[8]  += p2.x * w; acc[9]  += p2.y * w; acc[10] += p2.z * w; acc[11] += p2.w * w;
    acc[12] += p3.x * w; acc[13] += p3.y * w; acc[14] += p3.z * w; acc[15] += p3.w * w;
  }
  __syncthreads();          // all pT reads done before reuse as combine scratch
  if (jh == 1) {
#pragma unroll
    for (int r = 0; r < 16; r++) pT[c][r] = acc[r];
  }
  __syncthreads();
  if (jh == 0) {
#pragma unroll
    for (int r = 0; r < 16; r++) {
      float v = (acc[r] + pT[c][r]) * sinv[r];
      v = v > 0.f ? v : expm1f(v);   // elu
      out[(base + i0 + r) * ostride + ocoff + c] = v;
    }
  }
}

extern "C" void kernel_launch(void* const* d_in, const int* in_sizes, int n_in,
                              void* d_out, int out_size, void* d_ws, size_t ws_size,
                              hipStream_t stream) {
  const float* compound = (const float*)d_in[0];   // [64,512,34]
  const int*   adj      = (const int*)d_in[1];     // [64,512,512]
  const float* W_stack  = (const float*)d_in[2];   // [3,34,128]
  const float* a_stack  = (const float*)d_in[3];   // [3,256,1]
  const float* W_out    = (const float*)d_in[4];   // [384,128]
  const float* a_out    = (const float*)d_in[5];   // [256,1]
  const float* Wc       = (const float*)d_in[6];   // [128,256]
  const float* bc       = (const float*)d_in[7];   // [256]
  float* out = (float*)d_out;                      // [64,512,256]

  float* f     = (float*)d_ws;
  float* Wh    = f;                       // 4,194,304 floats
  float* src   = f + 4194304;             // 32,768
  float* dstv  = f + 4194304 + 32768;     // 32,768
  float* multi = f + 4194304 + 65536;     // 12,582,912
  float* x     = multi;                   // aliases multi (dead by then)

  for (int l = 0; l < 3; l++) {
    gemm_kernel<<<dim3(16, 1, 64), 256, 0, stream>>>(
        compound, W_stack + (long)l * 34 * 128, nullptr, Wh, 34, 128, 128, 0, 0);
    srcdst_kernel<<<8192, 256, 0, stream>>>(Wh, a_stack + (long)l * 256, src, dstv);
    attn_kernel<<<dim3(32, 64), 256, 0, stream>>>(Wh, adj, src, dstv, multi, 384, l * 128);
  }
  // output GAT layer
  gemm_kernel<<<dim3(16, 1, 64), 256, 0, stream>>>(multi, W_out, nullptr, Wh, 384, 128, 128, 0, 0);
  srcdst_kernel<<<8192, 256, 0, stream>>>(Wh, a_out, src, dstv);
  attn_kernel<<<dim3(32, 64), 256, 0, stream>>>(Wh, adj, src, dstv, x, 128, 0);
  // final linear + leaky_relu
  gemm_kernel<<<dim3(16, 2, 64), 256, 0, stream>>>(x, Wc, bc, out, 128, 256, 256, 0, 1);
}